// Round 10
// baseline (1203.915 us; speedup 1.0000x reference)
//
#include <hip/hip_runtime.h>

typedef float  f32x4  __attribute__((ext_vector_type(4)));
typedef float  f32x16 __attribute__((ext_vector_type(16)));
typedef int    i32x4  __attribute__((ext_vector_type(4)));
typedef int    i32x8  __attribute__((ext_vector_type(8)));

#define AS1 __attribute__((address_space(1)))
#define AS3 __attribute__((address_space(3)))

// ---- software float -> OCP e4m3fn (RNE), valid for |x| <= 448 ----
__device__ __forceinline__ unsigned int f2e4m3(float x){
    union{float f; unsigned u;} v; v.f = x;
    unsigned s = (v.u >> 24) & 0x80u;
    float ax = fabsf(x);
    if (ax > 448.0f) ax = 448.0f;
    if (ax < 0.015625f){
        int d = (int)__builtin_rintf(ax * 512.0f);
        return s | (unsigned)d;
    }
    v.f = ax;
    unsigned u = v.u + 0x7ffffu + ((v.u >> 20) & 1u);
    unsigned E = (u >> 23) - 120u;
    unsigned M = (u >> 20) & 7u;
    return s | (E << 3) | M;
}

// ---- 4 floats -> packed 4x e4m3 (HW cvt if available) ----
__device__ __forceinline__ unsigned int pk4(float x0, float x1, float x2, float x3){
#if __has_builtin(__builtin_amdgcn_cvt_pk_fp8_f32)
    int u = __builtin_amdgcn_cvt_pk_fp8_f32(x0, x1, 0, false);
    u     = __builtin_amdgcn_cvt_pk_fp8_f32(x2, x3, u, true);
    return (unsigned)u;
#else
    return f2e4m3(x0) | (f2e4m3(x1) << 8) | (f2e4m3(x2) << 16) | (f2e4m3(x3) << 24);
#endif
}

__device__ __forceinline__ void gload16(const unsigned char* g, const char* l){
    __builtin_amdgcn_global_load_lds((const AS1 void*)g, (AS3 void*)l, 16, 0, 0);
}

__device__ __forceinline__ i32x8 ld_frag(const char* p0, const char* p1){
    i32x4 lo = *(const i32x4*)p0;
    i32x4 hi = *(const i32x4*)p1;
    return __builtin_shufflevector(lo, hi, 0,1,2,3,4,5,6,7);
}

#define GBAR() do{ asm volatile("" ::: "memory"); __builtin_amdgcn_s_barrier(); \
                   asm volatile("" ::: "memory"); }while(0)
#define VMW(N)  asm volatile("s_waitcnt vmcnt(" #N ")" ::: "memory")

// ---------------------------------------------------------------------------
// Row l2-normalize [rows][1024] f32 -> fp8 e4m3 scaled by 16 (MX scale 2^-4).
// ---------------------------------------------------------------------------
__global__ __launch_bounds__(256) void norm_rows_fp8(const float* __restrict__ in,
                                                     unsigned int* __restrict__ out){
    const int row = blockIdx.x;
    const int t   = threadIdx.x;
    f32x4 x = ((const f32x4*)(in + (size_t)row * 1024))[t];
    float ss = x[0]*x[0] + x[1]*x[1] + x[2]*x[2] + x[3]*x[3];
    #pragma unroll
    for (int o = 32; o > 0; o >>= 1) ss += __shfl_xor(ss, o);
    __shared__ float red[4];
    if ((t & 63) == 0) red[t >> 6] = ss;
    __syncthreads();
    float tot = red[0] + red[1] + red[2] + red[3];
    float inv = 16.0f / fmaxf(sqrtf(tot), 1e-12f);
    out[(size_t)row * 256 + t] = pk4(x[0]*inv, x[1]*inv, x[2]*inv, x[3]*inv);
}

// ---------------------------------------------------------------------------
// Final in-place row l2-normalize of d_out [N][1024] f32.
// ---------------------------------------------------------------------------
__global__ __launch_bounds__(256) void norm_rows_f32(float* __restrict__ buf){
    const int row = blockIdx.x;
    const int t   = threadIdx.x;
    f32x4* p = (f32x4*)(buf + (size_t)row * 1024);
    f32x4 x = p[t];
    float ss = x[0]*x[0] + x[1]*x[1] + x[2]*x[2] + x[3]*x[3];
    #pragma unroll
    for (int o = 32; o > 0; o >>= 1) ss += __shfl_xor(ss, o);
    __shared__ float red[4];
    if ((t & 63) == 0) red[t >> 6] = ss;
    __syncthreads();
    float tot = red[0] + red[1] + red[2] + red[3];
    float inv = 1.0f / fmaxf(sqrtf(tot), 1e-12f);
    p[t] = x * inv;
}

// ---------------------------------------------------------------------------
// offset [C=2048][D=1024] f32 -> offt [D][C] fp8 e4m3 scaled by 64 (2^-6),
// fused sum(offset^2) -> atomicAdd(reg_out). Tile: 64(c) x 64(d).
// ---------------------------------------------------------------------------
__global__ __launch_bounds__(256) void transpose_off(const float* __restrict__ off,
                                                     unsigned char* __restrict__ offt,
                                                     float* __restrict__ reg_out){
    __shared__ unsigned char t_lds[64][68];
    const int t  = threadIdx.x;
    const int c0 = blockIdx.x * 64;
    const int d0 = blockIdx.y * 64;
    float ss = 0.f;
    #pragma unroll
    for (int p = 0; p < 4; ++p){
        int c  = p * 16 + (t >> 4);
        int dq = t & 15;
        f32x4 v = *(const f32x4*)(off + (size_t)(c0 + c) * 1024 + d0 + dq * 4);
        ss += v[0]*v[0] + v[1]*v[1] + v[2]*v[2] + v[3]*v[3];
        unsigned u = pk4(v[0]*64.0f, v[1]*64.0f, v[2]*64.0f, v[3]*64.0f);
        #pragma unroll
        for (int j = 0; j < 4; ++j) t_lds[dq * 4 + j][c] = (unsigned char)(u >> (8*j));
    }
    __syncthreads();
    #pragma unroll
    for (int p = 0; p < 4; ++p){
        int d  = p * 16 + (t >> 4);
        int cq = t & 15;
        unsigned int o = *(const unsigned int*)&t_lds[d][cq * 4];
        *(unsigned int*)(offt + (size_t)(d0 + d) * 2048 + c0 + cq * 4) = o;
    }
    #pragma unroll
    for (int o = 32; o > 0; o >>= 1) ss += __shfl_xor(ss, o);
    __shared__ float red[4];
    if ((t & 63) == 0) red[t >> 6] = ss;
    __syncthreads();
    if (t == 0) atomicAdd(reg_out, red[0] + red[1] + red[2] + red[3]);
}

// ---------------------------------------------------------------------------
// FP8 GEMM: acc[m][n] = 2^(SA-127)*2^(SB-127) * sum_k A[m][k]*B[n][k]
// (A,B fp8 e4m3, K-contiguous rows; lda/ldb in BYTES.)
// 256x128 tile, BK=64, 256 threads (4 waves 2Mx2N; wave tile 128x64).
// DOUBLE-buffered LDS: 2 x [A 16KB | B 8KB] = 48 KiB => THREE independent
// blocks/CU (144 <= 160 KiB; cross-block stall overlap, m114).
// mfma_scale_f32_32x32x64_f8f6f4, uniform scales. One barrier + one VMW(0)
// per K-tile; the drained loads were issued a full tile (~2500 cyc at 3-way
// CU sharing) earlier -> wait is ~free; cross-block TLP covers transients.
// Granule swizzle g ^= (row>>1)&3 via pre-swizzled global source.
// Safety (dbuf): stage(t+1)->b1 issues only after GBAR(t); every wave
// reached GBAR(t) only after its b1-consuming MFMAs at t-1, whose counted
// lgkm waits retired those reads -> no DMA-vs-read race.
// EPI==1: Wout = e4m3(exp(10*acc-10)*1024) via exp2+cvt_pk  (ldw bytes)
// EPI==2: Fout = Cadd + acc                                  (ldo floats)
// ---------------------------------------------------------------------------
template<int EPI, int SA, int SB>
__global__ __launch_bounds__(256, 3)
void gemm256(const unsigned char* __restrict__ A, int lda,
             const unsigned char* __restrict__ B, int ldb,
             int K,
             unsigned char* __restrict__ Wout, int ldw,
             const float* __restrict__ Cadd, float* __restrict__ Fout, int ldo)
{
    extern __shared__ char smem[];             // 2 x 24 KiB
    const int tid  = threadIdx.x;

    // ---- XCD-aware bijective remap ----
    int bx = blockIdx.x, by = blockIdx.y;
    {
        const int gx = gridDim.x, gy = gridDim.y;
        const int nwg = gx * gy;
        if ((nwg & 7) == 0){
            const int lid = bx + gx * by;
            const int q   = nwg >> 3;
            const int n   = (lid & 7) * q + (lid >> 3);
            const int sh  = 31 - __clz(gy);    // gy is a power of two
            bx = n >> sh;
            by = n & (gy - 1);
        }
    }
    const int m0   = bx * 256;
    const int n0   = by * 128;
    const int wid  = tid >> 6, lane = tid & 63;
    const int wr   = wid >> 1, wc = wid & 1;   // 2x2 waves, wave tile 128x64
    const int l31  = lane & 31, hg = lane >> 5;

    // ---- staging: A 16KB (256 rows x 64B), B 8KB (128 rows x 64B) ----
    const int srow = tid >> 2;
    const int sg   = (tid & 3) ^ ((tid >> 3) & 3);
    const unsigned char* sA = A + (size_t)(m0 + srow) * lda + sg * 16;
    const unsigned char* sB = B + (size_t)(n0 + srow) * ldb + sg * 16;
    const int lp = tid * 16;

    auto stgA = [&](char* wb, int ke){
        #pragma unroll
        for (int j = 0; j < 4; ++j)
            gload16(sA + (size_t)j * 64 * lda + ke, wb + j * 4096 + lp);
    };
    auto stgB = [&](char* wb, int ke){
        #pragma unroll
        for (int j = 0; j < 2; ++j)
            gload16(sB + (size_t)j * 64 * ldb + ke, wb + 16384 + j * 4096 + lp);
    };

    // ---- frag read offsets (swizzled) ----
    int aoff[4][2], boff[2][2];
    #pragma unroll
    for (int m = 0; m < 4; ++m){
        int row = wr * 128 + m * 32 + l31;
        int sw  = (row >> 1) & 3;
        aoff[m][0] = row * 64 + (((hg << 1) | 0) ^ sw) * 16;
        aoff[m][1] = row * 64 + (((hg << 1) | 1) ^ sw) * 16;
    }
    #pragma unroll
    for (int n = 0; n < 2; ++n){
        int row = wc * 64 + n * 32 + l31;
        int sw  = (row >> 1) & 3;
        boff[n][0] = 16384 + row * 64 + (((hg << 1) | 0) ^ sw) * 16;
        boff[n][1] = 16384 + row * 64 + (((hg << 1) | 1) ^ sw) * 16;
    }

    f32x16 acc[4][2] = {};
    const int nsteps = K >> 6;                 // BK = 64

#define RD_A(mb) { \
    fa[0] = ld_frag(b0 + aoff[(mb)][0],   b0 + aoff[(mb)][1]); \
    fa[1] = ld_frag(b0 + aoff[(mb)+1][0], b0 + aoff[(mb)+1][1]); }
#define RD_B()   { \
    fb[0] = ld_frag(b0 + boff[0][0], b0 + boff[0][1]); \
    fb[1] = ld_frag(b0 + boff[1][0], b0 + boff[1][1]); }
#define MFMA4(mb) { __builtin_amdgcn_s_setprio(1); \
    _Pragma("unroll") for (int mi = 0; mi < 2; ++mi) \
    _Pragma("unroll") for (int ni = 0; ni < 2; ++ni) \
        acc[(mb)+mi][ni] = __builtin_amdgcn_mfma_scale_f32_32x32x64_f8f6f4( \
            fa[mi], fb[ni], acc[(mb)+mi][ni], 0, 0, 0, SA, 0, SB); \
    __builtin_amdgcn_s_setprio(0); }

    i32x8 fa[2], fb[2];
    char* b0 = smem;
    char* b1 = smem + 24576;

    // ---- prologue: stage tile 0 (6 loads); drain; barrier ----
    stgA(b0, 0);  stgB(b0, 0);
    VMW(0);
    GBAR();

    int ke = 64;                               // k-byte offset of tile t+1
    #pragma unroll 1
    for (int t = 0; t < nsteps - 1; ++t){
        // stage tile t+1 into b1, interleaved with reads/MFMAs of tile t
        RD_A(0); RD_B();
        stgA(b1, ke);
        MFMA4(0);
        RD_A(2);
        stgB(b1, ke);
        MFMA4(2);
        VMW(0);                                // t+1's 6 loads landed (issued a tile ago)
        GBAR();
        char* tmp = b0; b0 = b1; b1 = tmp;
        ke += 64;
    }
    // last K-tile: no staging
    RD_A(0); RD_B();
    MFMA4(0);
    RD_A(2);
    MFMA4(2);

#undef RD_A
#undef RD_B
#undef MFMA4

    asm volatile("s_nop 7\n\ts_nop 7");

    // C/D layout (32x32): col = lane&31, row = (r&3) + 8*(r>>2) + 4*(lane>>5)
    #pragma unroll
    for (int m = 0; m < 4; ++m){
        #pragma unroll
        for (int n = 0; n < 2; ++n){
            const int grb = m0 + wr * 128 + m * 32;
            const int gc  = n0 + wc * 64  + n * 32 + l31;
            if (EPI == 1){
                #pragma unroll
                for (int q = 0; q < 4; ++q){
                    const int row0 = grb + 8 * q + 4 * hg;   // rows row0..row0+3
                    float w0 = exp2f(fmaf(14.4269504f, acc[m][n][4*q+0], -4.4269504f));
                    float w1 = exp2f(fmaf(14.4269504f, acc[m][n][4*q+1], -4.4269504f));
                    float w2 = exp2f(fmaf(14.4269504f, acc[m][n][4*q+2], -4.4269504f));
                    float w3 = exp2f(fmaf(14.4269504f, acc[m][n][4*q+3], -4.4269504f));
                    unsigned u = pk4(w0, w1, w2, w3);
                    unsigned char* p = Wout + (size_t)row0 * ldw + gc;
                    p[0]                = (unsigned char)u;
                    p[(size_t)ldw]      = (unsigned char)(u >> 8);
                    p[(size_t)ldw * 2]  = (unsigned char)(u >> 16);
                    p[(size_t)ldw * 3]  = (unsigned char)(u >> 24);
                }
            } else {
                #pragma unroll
                for (int r = 0; r < 16; ++r){
                    const int row = (r & 3) + 8 * (r >> 2) + 4 * hg;
                    Fout[(size_t)(grb + row) * ldo + gc] =
                        Cadd[(size_t)(grb + row) * ldo + gc] + acc[m][n][r];
                }
            }
        }
    }
}

// ---------------------------------------------------------------------------
extern "C" void kernel_launch(void* const* d_in, const int* in_sizes, int n_in,
                              void* d_out, int out_size, void* d_ws, size_t ws_size,
                              hipStream_t stream)
{
    (void)n_in; (void)out_size;
    const float* inp = (const float*)d_in[0];
    const float* pos = (const float*)d_in[1];
    const float* off = (const float*)d_in[2];
    float* out = (float*)d_out;

    const int D = 1024, C = 2048;
    const int N = in_sizes[0] / D;            // 32768

    // workspace (bytes): b_fp8[C*D] | offt[D*C] | a_fp8[Mc*D] | w_buf[Mc*C]
    unsigned char* b_fp8 = (unsigned char*)d_ws;
    unsigned char* offt  = b_fp8 + (size_t)C * D;
    unsigned char* a_fp8 = offt + (size_t)D * C;
    size_t fixed = (size_t)C * D * 2;
    size_t avail = ws_size > fixed ? ws_size - fixed : 0;
    int Mc = 256;
    for (int cand = N; cand >= 256; cand >>= 1){
        if ((size_t)cand * (size_t)(D + C) <= avail){ Mc = cand; break; }
    }
    if (Mc > N) Mc = N;
    unsigned char* w_buf = a_fp8 + (size_t)Mc * D;

    // scales (e8m0, 2^(b-127)): GEMM1 a,pos *16 -> 123,123;
    // GEMM2 W *1024 -> 117, offt *64 -> 121.
    hipFuncSetAttribute(reinterpret_cast<const void*>(&gemm256<1,123,123>),
                        hipFuncAttributeMaxDynamicSharedMemorySize, 49152);
    hipFuncSetAttribute(reinterpret_cast<const void*>(&gemm256<2,117,121>),
                        hipFuncAttributeMaxDynamicSharedMemorySize, 49152);

    float* reg_out = out + (size_t)N * D;
    hipMemsetAsync(reg_out, 0, sizeof(float), stream);

    transpose_off<<<dim3(C / 64, D / 64), 256, 0, stream>>>(off, offt, reg_out);
    norm_rows_fp8<<<C, 256, 0, stream>>>(pos, (unsigned int*)b_fp8);

    for (int r0 = 0; r0 < N; r0 += Mc){
        norm_rows_fp8<<<Mc, 256, 0, stream>>>(inp + (size_t)r0 * D, (unsigned int*)a_fp8);
        // GEMM1: W[Mc][C] = e4m3(1024 * exp(10*(a.b^T) - 10))
        gemm256<1,123,123><<<dim3(Mc / 256, C / 128), 256, 49152, stream>>>(
            a_fp8, D, b_fp8, D, D, w_buf, C, nullptr, nullptr, 0);
        // GEMM2: out[Mc][D] = inp + (2^-16 scaled) W . offt^T
        gemm256<2,117,121><<<dim3(Mc / 256, D / 128), 256, 49152, stream>>>(
            w_buf, C, offt, C, C, nullptr, 0, inp + (size_t)r0 * D, out + (size_t)r0 * D, D);
    }
    norm_rows_f32<<<N, 256, 0, stream>>>(out);
}

// Round 11
// 279.436 us; speedup vs baseline: 4.3084x; 4.3084x over previous
//
#include <hip/hip_runtime.h>

typedef float  f32x4  __attribute__((ext_vector_type(4)));
typedef float  f32x16 __attribute__((ext_vector_type(16)));
typedef int    i32x4  __attribute__((ext_vector_type(4)));
typedef int    i32x8  __attribute__((ext_vector_type(8)));

// ---- software float -> OCP e4m3fn (RNE), valid for |x| <= 448 ----
__device__ __forceinline__ unsigned int f2e4m3(float x){
    union{float f; unsigned u;} v; v.f = x;
    unsigned s = (v.u >> 24) & 0x80u;
    float ax = fabsf(x);
    if (ax > 448.0f) ax = 448.0f;
    if (ax < 0.015625f){
        int d = (int)__builtin_rintf(ax * 512.0f);
        return s | (unsigned)d;
    }
    v.f = ax;
    unsigned u = v.u + 0x7ffffu + ((v.u >> 20) & 1u);
    unsigned E = (u >> 23) - 120u;
    unsigned M = (u >> 20) & 7u;
    return s | (E << 3) | M;
}

// ---- 4 floats -> packed 4x e4m3 (HW cvt if available) ----
__device__ __forceinline__ unsigned int pk4(float x0, float x1, float x2, float x3){
#if __has_builtin(__builtin_amdgcn_cvt_pk_fp8_f32)
    int u = __builtin_amdgcn_cvt_pk_fp8_f32(x0, x1, 0, false);
    u     = __builtin_amdgcn_cvt_pk_fp8_f32(x2, x3, u, true);
    return (unsigned)u;
#else
    return f2e4m3(x0) | (f2e4m3(x1) << 8) | (f2e4m3(x2) << 16) | (f2e4m3(x3) << 24);
#endif
}

__device__ __forceinline__ i32x8 ld_frag(const char* p0, const char* p1){
    i32x4 lo = *(const i32x4*)p0;
    i32x4 hi = *(const i32x4*)p1;
    return __builtin_shufflevector(lo, hi, 0,1,2,3,4,5,6,7);
}

// ---------------------------------------------------------------------------
// Fragment-linear fp8 layout for an operand X[rows][K] consumed by
// mfma_scale 32x32x64: frag f = row>>5 (32 rows), k-tile t (64 bytes).
// chunk(f,t) = 2048 contiguous bytes at ((f*NT)+t)*2048; within chunk,
// lane l holds bytes [l*32, l*32+32) = row (l&31), k [(l>>5)*32, +32).
// Wave frag load = 64 lanes x 32B contiguous 2KB, fully coalesced.
// ---------------------------------------------------------------------------

// ---------------------------------------------------------------------------
// Row l2-normalize [rows][1024] f32 -> fp8 e4m3 *16 (scale 2^-4),
// stored FRAGMENT-LINEAR with NT=16. One 256-thread block per row.
// ---------------------------------------------------------------------------
__global__ __launch_bounds__(256) void norm_rows_fp8(const float* __restrict__ in,
                                                     unsigned char* __restrict__ out){
    const int row = blockIdx.x;
    const int t   = threadIdx.x;
    f32x4 x = ((const f32x4*)(in + (size_t)row * 1024))[t];
    float ss = x[0]*x[0] + x[1]*x[1] + x[2]*x[2] + x[3]*x[3];
    #pragma unroll
    for (int o = 32; o > 0; o >>= 1) ss += __shfl_xor(ss, o);
    __shared__ float red[4];
    if ((t & 63) == 0) red[t >> 6] = ss;
    __syncthreads();
    float tot = red[0] + red[1] + red[2] + red[3];
    float inv = 16.0f / fmaxf(sqrtf(tot), 1e-12f);
    unsigned u = pk4(x[0]*inv, x[1]*inv, x[2]*inv, x[3]*inv);
    // thread covers k-bytes 4t..4t+3: tile = t>>4, k-half = (t>>3)&1
    size_t addr = ((size_t)(row >> 5) * 16 + (t >> 4)) * 2048
                + (size_t)((t >> 3) & 1) * 1024
                + (size_t)(row & 31) * 32 + ((4 * t) & 31);
    *(unsigned int*)(out + addr) = u;
}

// ---------------------------------------------------------------------------
// Final in-place row l2-normalize of d_out [N][1024] f32.
// ---------------------------------------------------------------------------
__global__ __launch_bounds__(256) void norm_rows_f32(float* __restrict__ buf){
    const int row = blockIdx.x;
    const int t   = threadIdx.x;
    f32x4* p = (f32x4*)(buf + (size_t)row * 1024);
    f32x4 x = p[t];
    float ss = x[0]*x[0] + x[1]*x[1] + x[2]*x[2] + x[3]*x[3];
    #pragma unroll
    for (int o = 32; o > 0; o >>= 1) ss += __shfl_xor(ss, o);
    __shared__ float red[4];
    if ((t & 63) == 0) red[t >> 6] = ss;
    __syncthreads();
    float tot = red[0] + red[1] + red[2] + red[3];
    float inv = 1.0f / fmaxf(sqrtf(tot), 1e-12f);
    p[t] = x * inv;
}

// ---------------------------------------------------------------------------
// offset [C=2048][D=1024] f32 -> offt fragment-linear fp8 *64 (2^-6):
// rows = d (1024), K = c (2048), NT=32. Fused sum(offset^2) atomic.
// Tile 64(c) x 64(d): block emits 2 frag-chunks (4KB), fully coalesced.
// ---------------------------------------------------------------------------
__global__ __launch_bounds__(256) void transpose_off(const float* __restrict__ off,
                                                     unsigned char* __restrict__ offt,
                                                     float* __restrict__ reg_out){
    __shared__ unsigned char t_lds[64][68];
    const int t  = threadIdx.x;
    const int c0 = blockIdx.x * 64;
    const int d0 = blockIdx.y * 64;
    float ss = 0.f;
    #pragma unroll
    for (int p = 0; p < 4; ++p){
        int c  = p * 16 + (t >> 4);
        int dq = t & 15;
        f32x4 v = *(const f32x4*)(off + (size_t)(c0 + c) * 1024 + d0 + dq * 4);
        ss += v[0]*v[0] + v[1]*v[1] + v[2]*v[2] + v[3]*v[3];
        unsigned u = pk4(v[0]*64.0f, v[1]*64.0f, v[2]*64.0f, v[3]*64.0f);
        #pragma unroll
        for (int j = 0; j < 4; ++j) t_lds[dq * 4 + j][c] = (unsigned char)(u >> (8*j));
    }
    __syncthreads();
    // write 2 frag-chunks: addr = ((f)*32 + c0>>6)*2048 + rem, rem in [0,2048)
    #pragma unroll
    for (int i = 0; i < 4; ++i){
        int byte_o = (t + 256 * i) * 4;
        int fs  = byte_o >> 11;
        int rem = byte_o & 2047;
        int dl  = fs * 32 + ((rem >> 5) & 31);
        int cl  = ((rem >> 10) & 1) * 32 + (rem & 31);
        unsigned int v = *(const unsigned int*)&t_lds[dl][cl];
        size_t f = (size_t)((d0 >> 5) + fs);
        *(unsigned int*)(offt + (f * 32 + (c0 >> 6)) * 2048 + rem) = v;
    }
    #pragma unroll
    for (int o = 32; o > 0; o >>= 1) ss += __shfl_xor(ss, o);
    __shared__ float red[4];
    if ((t & 63) == 0) red[t >> 6] = ss;
    __syncthreads();
    if (t == 0) atomicAdd(reg_out, red[0] + red[1] + red[2] + red[3]);
}

// ---------------------------------------------------------------------------
// FP8 GEMM, NO-LDS / NO-BARRIER: operands fragment-linear (NT = K/64).
// 256 threads = 4 independent waves (2Mx2N), wave tile 128x64, block 256x128.
// Each wave streams its A/B fragments global->register (coalesced 2KB/frag,
// B fully L2-resident, A L1-shared between wc pair) with a ping-pong
// register double-buffer; compiler emits counted vmcnt off register deps.
// mfma_scale_f32_32x32x64_f8f6f4, uniform scales SA,SB (e8m0).
// EPI==1: Wout = e4m3(exp(10*acc-10)*1024), FRAGMENT-LINEAR (wNT k-tiles)
// EPI==2: Fout = Cadd + acc, row-major f32 (ldo)
// ---------------------------------------------------------------------------
template<int EPI, int SA, int SB, int NT>
__global__ __launch_bounds__(256, 2)
void gemm_fl(const unsigned char* __restrict__ A,
             const unsigned char* __restrict__ B,
             unsigned char* __restrict__ Wout, int wNT,
             const float* __restrict__ Cadd,
             float* __restrict__ Fout, int ldo)
{
    const int tid = threadIdx.x;

    // ---- XCD-aware bijective remap (same-m blocks contiguous per XCD) ----
    int bx = blockIdx.x, by = blockIdx.y;
    {
        const int gx = gridDim.x, gy = gridDim.y;
        const int nwg = gx * gy;
        if ((nwg & 7) == 0){
            const int lid = bx + gx * by;
            const int q   = nwg >> 3;
            const int n   = (lid & 7) * q + (lid >> 3);
            const int sh  = 31 - __clz(gy);    // gy is a power of two
            bx = n >> sh;
            by = n & (gy - 1);
        }
    }
    const int m0  = bx * 256;
    const int n0  = by * 128;
    const int wid = tid >> 6, lane = tid & 63;
    const int wr  = wid >> 1, wc = wid & 1;    // 2x2 waves, wave tile 128x64
    const int l31 = lane & 31, hg = lane >> 5;

    const char* pA[4];
    const char* pB[2];
    #pragma unroll
    for (int m = 0; m < 4; ++m)
        pA[m] = (const char*)A
              + ((size_t)((m0 + wr * 128 + m * 32) >> 5) * NT) * 2048 + lane * 32;
    #pragma unroll
    for (int n = 0; n < 2; ++n)
        pB[n] = (const char*)B
              + ((size_t)((n0 + wc * 64 + n * 32) >> 5) * NT) * 2048 + lane * 32;

    f32x16 acc[4][2] = {};
    i32x8 a0[4], b0[2], a1[4], b1[2];

    // prologue: tile 0 -> set0
    #pragma unroll
    for (int m = 0; m < 4; ++m) a0[m] = ld_frag(pA[m], pA[m] + 16);
    #pragma unroll
    for (int n = 0; n < 2; ++n) b0[n] = ld_frag(pB[n], pB[n] + 16);

#define MFMA8(av, bv) { __builtin_amdgcn_s_setprio(1); \
    _Pragma("unroll") for (int mi = 0; mi < 4; ++mi) \
    _Pragma("unroll") for (int ni = 0; ni < 2; ++ni) \
        acc[mi][ni] = __builtin_amdgcn_mfma_scale_f32_32x32x64_f8f6f4( \
            av[mi], bv[ni], acc[mi][ni], 0, 0, 0, SA, 0, SB); \
    __builtin_amdgcn_s_setprio(0); }

    #pragma unroll 1
    for (int t = 0; t < NT; t += 2){
        const size_t o1 = (size_t)(t + 1) * 2048;      // t+1 <= NT-1 always
        #pragma unroll
        for (int m = 0; m < 4; ++m) a1[m] = ld_frag(pA[m] + o1, pA[m] + o1 + 16);
        #pragma unroll
        for (int n = 0; n < 2; ++n) b1[n] = ld_frag(pB[n] + o1, pB[n] + o1 + 16);
        MFMA8(a0, b0);
        const size_t o2 = (size_t)(t + 2 < NT ? t + 2 : NT - 1) * 2048;  // clamp: in-bounds
        #pragma unroll
        for (int m = 0; m < 4; ++m) a0[m] = ld_frag(pA[m] + o2, pA[m] + o2 + 16);
        #pragma unroll
        for (int n = 0; n < 2; ++n) b0[n] = ld_frag(pB[n] + o2, pB[n] + o2 + 16);
        MFMA8(a1, b1);
    }
#undef MFMA8

    asm volatile("s_nop 7\n\ts_nop 7");

    // C/D layout (32x32): col = lane&31, row = (r&3) + 8*(r>>2) + 4*(lane>>5)
    if (EPI == 1){
        // W fragment-linear: frag = wrow>>5 (wNT k-tiles), k-tile = gc>>6,
        // k-half = n (since (n0+wc*64)%64==0), pos = l31.
        const int tq = (n0 + wc * 64) >> 6;
        #pragma unroll
        for (int m = 0; m < 4; ++m){
            const size_t fW = (size_t)((m0 + wr * 128 + m * 32) >> 5);
            #pragma unroll
            for (int n = 0; n < 2; ++n){
                unsigned char* base = Wout + (fW * wNT + tq) * 2048
                                    + (size_t)n * 1024 + l31;
                #pragma unroll
                for (int q = 0; q < 4; ++q){
                    float w0 = exp2f(fmaf(14.4269504f, acc[m][n][4*q+0], -4.4269504f));
                    float w1 = exp2f(fmaf(14.4269504f, acc[m][n][4*q+1], -4.4269504f));
                    float w2 = exp2f(fmaf(14.4269504f, acc[m][n][4*q+2], -4.4269504f));
                    float w3 = exp2f(fmaf(14.4269504f, acc[m][n][4*q+3], -4.4269504f));
                    unsigned u = pk4(w0, w1, w2, w3);
                    unsigned char* p = base + (size_t)(8 * q + 4 * hg) * 32;
                    p[0]  = (unsigned char)u;
                    p[32] = (unsigned char)(u >> 8);
                    p[64] = (unsigned char)(u >> 16);
                    p[96] = (unsigned char)(u >> 24);
                }
            }
        }
    } else {
        #pragma unroll
        for (int m = 0; m < 4; ++m){
            #pragma unroll
            for (int n = 0; n < 2; ++n){
                const int grb = m0 + wr * 128 + m * 32;
                const int gc  = n0 + wc * 64 + n * 32 + l31;
                #pragma unroll
                for (int r = 0; r < 16; ++r){
                    const int row = (r & 3) + 8 * (r >> 2) + 4 * hg;
                    Fout[(size_t)(grb + row) * ldo + gc] =
                        Cadd[(size_t)(grb + row) * ldo + gc] + acc[m][n][r];
                }
            }
        }
    }
}

// ---------------------------------------------------------------------------
extern "C" void kernel_launch(void* const* d_in, const int* in_sizes, int n_in,
                              void* d_out, int out_size, void* d_ws, size_t ws_size,
                              hipStream_t stream)
{
    (void)n_in; (void)out_size;
    const float* inp = (const float*)d_in[0];
    const float* pos = (const float*)d_in[1];
    const float* off = (const float*)d_in[2];
    float* out = (float*)d_out;

    const int D = 1024, C = 2048;
    const int N = in_sizes[0] / D;            // 32768

    // workspace (bytes): b_fp8[C*D] | offt[D*C] | a_fp8[Mc*D] | w_buf[Mc*C]
    unsigned char* b_fp8 = (unsigned char*)d_ws;
    unsigned char* offt  = b_fp8 + (size_t)C * D;
    unsigned char* a_fp8 = offt + (size_t)D * C;
    size_t fixed = (size_t)C * D * 2;
    size_t avail = ws_size > fixed ? ws_size - fixed : 0;
    int Mc = 256;
    for (int cand = N; cand >= 256; cand >>= 1){
        if ((size_t)cand * (size_t)(D + C) <= avail){ Mc = cand; break; }
    }
    if (Mc > N) Mc = N;
    unsigned char* w_buf = a_fp8 + (size_t)Mc * D;

    float* reg_out = out + (size_t)N * D;
    hipMemsetAsync(reg_out, 0, sizeof(float), stream);

    transpose_off<<<dim3(C / 64, D / 64), 256, 0, stream>>>(off, offt, reg_out);
    norm_rows_fp8<<<C, 256, 0, stream>>>(pos, b_fp8);

    // scales (e8m0, 2^(b-127)): GEMM1 a,pos *16 -> 123,123;
    // GEMM2 W *1024 -> 117, offt *64 -> 121.
    for (int r0 = 0; r0 < N; r0 += Mc){
        norm_rows_fp8<<<Mc, 256, 0, stream>>>(inp + (size_t)r0 * D, a_fp8);
        // GEMM1: W[Mc][C] = e4m3(1024 * exp(10*(a.b^T) - 10)), frag-linear wNT=32
        gemm_fl<1,123,123,16><<<dim3(Mc / 256, C / 128), 256, 0, stream>>>(
            a_fp8, b_fp8, w_buf, C / 64, nullptr, nullptr, 0);
        // GEMM2: out[Mc][D] = inp + (2^-16 scaled) W . offt^T
        gemm_fl<2,117,121,32><<<dim3(Mc / 256, D / 128), 256, 0, stream>>>(
            w_buf, offt, nullptr, 0, inp + (size_t)r0 * D, out + (size_t)r0 * D, D);
    }
    norm_rows_f32<<<N, 256, 0, stream>>>(out);
}